// Round 1
// baseline (145.642 us; speedup 1.0000x reference)
//
#include <hip/hip_runtime.h>

// Dims: b=16, n=1024, EMB=1024, INNER=128, HEADS=8, HD=16
#define LOG2E 1.44269504088896340736f
#define QSCALE (0.08838834764831845f * LOG2E)   // INNER^-0.5 * log2(e)

using short8 = __attribute__((ext_vector_type(8))) short;
using f32x4  = __attribute__((ext_vector_type(4))) float;
using f32x16 = __attribute__((ext_vector_type(16))) float;

union U16B { uint4 u; short8 s; };

static __device__ __forceinline__ unsigned short f2bf(float f){
  union { float f; unsigned int i; } c; c.f = f;
  unsigned int i = c.i;
  i += 0x7fffu + ((i >> 16) & 1u);   // RNE
  return (unsigned short)(i >> 16);
}

// ---------------- K1: LayerNorm -> xn (bf16) ----------------
__global__ __launch_bounds__(256) void k_ln(const float* __restrict__ x,
                                            const float* __restrict__ gamma,
                                            const float* __restrict__ beta,
                                            unsigned short* __restrict__ xn){
  const int tok = blockIdx.x;
  const int tid = threadIdx.x;
  float4 v = ((const float4*)(x + (size_t)tok*1024))[tid];
  float s  = v.x+v.y+v.z+v.w;
  float s2 = v.x*v.x+v.y*v.y+v.z*v.z+v.w*v.w;
  #pragma unroll
  for (int o=32;o;o>>=1){ s += __shfl_xor(s,o); s2 += __shfl_xor(s2,o); }
  __shared__ float red[8];
  if ((tid&63)==0){ red[tid>>6] = s; red[4+(tid>>6)] = s2; }
  __syncthreads();
  s  = red[0]+red[1]+red[2]+red[3];
  s2 = red[4]+red[5]+red[6]+red[7];
  float mu   = s*(1.0f/1024.0f);
  float rstd = rsqrtf(s2*(1.0f/1024.0f) - mu*mu + 1e-5f);
  float4 g = ((const float4*)gamma)[tid];
  float4 b = ((const float4*)beta)[tid];
  ushort4 o;
  o.x = f2bf((v.x-mu)*rstd*g.x + b.x);
  o.y = f2bf((v.y-mu)*rstd*g.y + b.y);
  o.z = f2bf((v.z-mu)*rstd*g.z + b.z);
  o.w = f2bf((v.w-mu)*rstd*g.w + b.w);
  ((ushort4*)(xn + (size_t)tok*1024))[tid] = o;
}

// ---------------- K2: QKV GEMM (M=16384,K=1024,N=384) ----------------
// grid (256, 3): 64-row M-blocks x 128-col section (0=q,1=k,2=v)
__global__ __launch_bounds__(256) void k_qkv(const unsigned short* __restrict__ xn,
                                             const float* __restrict__ wqkv,
                                             unsigned short* __restrict__ q,
                                             unsigned short* __restrict__ kbuf,
                                             unsigned short* __restrict__ vT){
  __shared__ __align__(16) unsigned short sm[64*64 + 128*64]; // A 8KB + Bt 16KB
  unsigned short* sA = sm;          // [64 tok][64 k], 128B rows, swz (row&7)<<4
  unsigned short* sB = sm + 4096;   // Bt [128 n][64 k], 128B rows, swz (n&7)<<4
  const int tid = threadIdx.x;
  const int w = tid>>6, l = tid&63;
  const int m0 = blockIdx.x*64;
  const int sec = blockIdx.y;
  const int nb = sec*128;
  const int wm = (w>>1)*32, wn = (w&1)*64;
  f32x4 acc[2][4] = {};
  for (int k0=0; k0<1024; k0+=64){
    #pragma unroll
    for (int it=0; it<2; ++it){                  // stage A (bf16 direct)
      int task = it*256 + tid;
      int row = task>>3, ch = task&7;
      uint4 vv = *(const uint4*)(xn + (size_t)(m0+row)*1024 + k0 + ch*8);
      *(uint4*)((char*)sA + row*128 + ((ch*16) ^ ((row&7)<<4))) = vv;
    }
    #pragma unroll
    for (int it=0; it<4; ++it){                  // stage B transposed + cvt
      int task = it*256 + tid;
      int kp = task>>5, n4 = (task&31)*4;
      const float* wp = wqkv + (size_t)(k0 + 2*kp)*384 + nb + n4;
      float4 wa = *(const float4*)wp;
      float4 wb = *(const float4*)(wp + 384);
      unsigned int d0 = (unsigned int)f2bf(wa.x) | ((unsigned int)f2bf(wb.x)<<16);
      unsigned int d1 = (unsigned int)f2bf(wa.y) | ((unsigned int)f2bf(wb.y)<<16);
      unsigned int d2 = (unsigned int)f2bf(wa.z) | ((unsigned int)f2bf(wb.z)<<16);
      unsigned int d3 = (unsigned int)f2bf(wa.w) | ((unsigned int)f2bf(wb.w)<<16);
      int cb = kp*4;
      *(unsigned int*)((char*)sB + (n4+0)*128 + (cb ^ (((n4+0)&7)<<4))) = d0;
      *(unsigned int*)((char*)sB + (n4+1)*128 + (cb ^ (((n4+1)&7)<<4))) = d1;
      *(unsigned int*)((char*)sB + (n4+2)*128 + (cb ^ (((n4+2)&7)<<4))) = d2;
      *(unsigned int*)((char*)sB + (n4+3)*128 + (cb ^ (((n4+3)&7)<<4))) = d3;
    }
    __syncthreads();
    #pragma unroll
    for (int s=0; s<2; ++s){
      short8 af[2], bfr[4];
      #pragma unroll
      for (int i=0;i<2;i++){
        int row = wm + i*16 + (l&15);
        U16B t_; t_.u = *(const uint4*)((const char*)sA + row*128 + ((s*64 + (l>>4)*16) ^ ((row&7)<<4)));
        af[i] = t_.s;
      }
      #pragma unroll
      for (int j=0;j<4;j++){
        int col = wn + j*16 + (l&15);
        U16B t_; t_.u = *(const uint4*)((const char*)sB + col*128 + ((s*64 + (l>>4)*16) ^ ((col&7)<<4)));
        bfr[j] = t_.s;
      }
      #pragma unroll
      for (int i=0;i<2;i++)
        #pragma unroll
        for (int j=0;j<4;j++)
          acc[i][j] = __builtin_amdgcn_mfma_f32_16x16x32_bf16(af[i], bfr[j], acc[i][j], 0,0,0);
    }
    __syncthreads();
  }
  // Epilogue: re-layout via LDS, write head-major buffers
  const int b  = m0 >> 10;
  const int n0 = m0 & 1023;
  const float scale = (sec==0) ? QSCALE : 1.0f;
  if (sec < 2){
    // LDS [tok][f]: 64 x 128 ushorts, 256B rows, swz (tok&15)<<4
    #pragma unroll
    for (int fm=0; fm<2; ++fm)
      #pragma unroll
      for (int fn=0; fn<4; ++fn){
        int colf = wn + fn*16 + (l&15);
        #pragma unroll
        for (int i=0;i<4;i++){
          int row = wm + fm*16 + (l>>4)*4 + i;
          *(unsigned short*)((char*)sm + row*256 + ((2*colf) ^ ((row&15)<<4))) = f2bf(acc[fm][fn][i]*scale);
        }
      }
    __syncthreads();
    unsigned short* dst = (sec==0) ? q : kbuf;
    #pragma unroll
    for (int it=0; it<4; ++it){
      int chunk = it*256 + tid;          // 64 rows x 16 chunks
      int tokl = chunk>>4, cc = chunk&15;
      uint4 vv = *(const uint4*)((const char*)sm + tokl*256 + ((cc*16) ^ ((tokl&15)<<4)));
      int f = cc*8;
      int h = f>>4, d0 = f&15;
      *(uint4*)(dst + ((size_t)(b*8 + h)*1024 + n0 + tokl)*16 + d0) = vv;
    }
  } else {
    // v transposed: LDS [f][tok]: 128 x 64 ushorts, 128B rows, swz (f&7)<<4
    #pragma unroll
    for (int fm=0; fm<2; ++fm)
      #pragma unroll
      for (int fn=0; fn<4; ++fn){
        int colf = wn + fn*16 + (l&15);
        int r0 = wm + fm*16 + (l>>4)*4;
        ushort4 pk;
        pk.x = f2bf(acc[fm][fn][0]); pk.y = f2bf(acc[fm][fn][1]);
        pk.z = f2bf(acc[fm][fn][2]); pk.w = f2bf(acc[fm][fn][3]);
        *(ushort4*)((char*)sm + colf*128 + ((2*r0) ^ ((colf&7)<<4))) = pk;
      }
    __syncthreads();
    #pragma unroll
    for (int it=0; it<4; ++it){
      int chunk = it*256 + tid;          // 128 f x 8 chunks
      int f = chunk>>3, cc = chunk&7;
      uint4 vv = *(const uint4*)((const char*)sm + f*128 + ((cc*16) ^ ((f&7)<<4)));
      int h = f>>4, d = f&15;
      *(uint4*)(vT + ((size_t)(b*8 + h)*16 + d)*1024 + n0 + cc*8) = vv;
    }
  }
}

// ---------------- K3: flash attention (swapped QK^T, lane-local softmax) ----------------
// grid (128 bh, 8 qchunk), 4 waves x 32 q-rows
__global__ __launch_bounds__(256) void k_attn(const unsigned short* __restrict__ q,
                                              const unsigned short* __restrict__ kbuf,
                                              const unsigned short* __restrict__ vT,
                                              unsigned short* __restrict__ aout){
  const int bh = blockIdx.x;
  const int qc = blockIdx.y;
  const int w = threadIdx.x>>6, l = threadIdx.x&63;
  const int l31 = l&31, hi = l>>5;
  const int h = bh & 7;
  const int qrow = qc*128 + w*32 + l31;
  U16B qf_u; qf_u.u = *(const uint4*)(q + ((size_t)bh*1024 + qrow)*16 + hi*8);
  const short8 qf = qf_u.s;
  const unsigned short* kp0 = kbuf + (size_t)bh*1024*16;
  const unsigned short* vp0 = vT + (size_t)bh*16*1024;
  const bool vok = (l31 < 16);
  const unsigned short* vrow = vp0 + (size_t)(l31 & 15)*1024;
  f32x16 acc = {};
  float m = -1e30f, ssum = 0.0f;
  for (int t=0; t<32; ++t){
    U16B kf_u; kf_u.u = *(const uint4*)(kp0 + (size_t)(t*32 + l31)*16 + hi*8);
    f32x16 zz = {};
    f32x16 sv = __builtin_amdgcn_mfma_f32_32x32x16_bf16(kf_u.s, qf, zz, 0,0,0);
    // online softmax: lane holds 16 of 32 k-positions for its q-row
    float tm = sv[0];
    #pragma unroll
    for (int r=1;r<16;r++) tm = fmaxf(tm, sv[r]);
    tm = fmaxf(tm, __shfl_xor(tm, 32));
    float mnew = fmaxf(m, tm);
    float sc = __builtin_amdgcn_exp2f(m - mnew);
    m = mnew;
    ssum *= sc;
    #pragma unroll
    for (int r=0;r<16;r++) acc[r] *= sc;
    float p[16];
    #pragma unroll
    for (int r=0;r<16;r++){ p[r] = __builtin_amdgcn_exp2f(sv[r] - m); ssum += p[r]; }
    unsigned int u[8];
    #pragma unroll
    for (int j=0;j<8;j++){
      asm("v_cvt_pk_bf16_f32 %0, %1, %2" : "=v"(u[j]) : "v"(p[2*j]), "v"(p[2*j+1]));
    }
    // weave P^T fragments (kpos 0..15 and 16..31) across lane halves
    unsigned int x0 = __shfl_xor(u[0],32), x1 = __shfl_xor(u[1],32);
    unsigned int x2 = __shfl_xor(u[2],32), x3 = __shfl_xor(u[3],32);
    U16B p0;
    p0.u.x = hi ? x2 : u[0];
    p0.u.y = hi ? x3 : u[1];
    p0.u.z = hi ? u[2] : x0;
    p0.u.w = hi ? u[3] : x1;
    unsigned int x4 = __shfl_xor(u[4],32), x5 = __shfl_xor(u[5],32);
    unsigned int x6 = __shfl_xor(u[6],32), x7 = __shfl_xor(u[7],32);
    U16B p1;
    p1.u.x = hi ? x6 : u[4];
    p1.u.y = hi ? x7 : u[5];
    p1.u.z = hi ? u[6] : x4;
    p1.u.w = hi ? u[7] : x5;
    U16B v0, v1;
    v0.u = make_uint4(0,0,0,0); v1.u = make_uint4(0,0,0,0);
    if (vok){
      v0.u = *(const uint4*)(vrow + (size_t)t*32 + hi*8);
      v1.u = *(const uint4*)(vrow + (size_t)t*32 + 16 + hi*8);
    }
    acc = __builtin_amdgcn_mfma_f32_32x32x16_bf16(v0.s, p0.s, acc, 0,0,0);
    acc = __builtin_amdgcn_mfma_f32_32x32x16_bf16(v1.s, p1.s, acc, 0,0,0);
  }
  ssum += __shfl_xor(ssum, 32);
  float inv = 1.0f/ssum;
  const size_t tok = (size_t)(bh>>3)*1024 + qrow;
  ushort4 o;
  o.x = f2bf(acc[0]*inv); o.y = f2bf(acc[1]*inv); o.z = f2bf(acc[2]*inv); o.w = f2bf(acc[3]*inv);
  *(ushort4*)(aout + tok*128 + h*16 + hi*4) = o;
  o.x = f2bf(acc[4]*inv); o.y = f2bf(acc[5]*inv); o.z = f2bf(acc[6]*inv); o.w = f2bf(acc[7]*inv);
  *(ushort4*)(aout + tok*128 + h*16 + 8 + hi*4) = o;
}

// ---------------- K4: out-projection (M=16384,K=128,N=1024) + bias ----------------
// grid (128, 8)
__global__ __launch_bounds__(256) void k_proj(const unsigned short* __restrict__ aout,
                                              const float* __restrict__ wproj,
                                              const float* __restrict__ bias,
                                              float* __restrict__ out){
  __shared__ __align__(16) unsigned short sA[128*128]; // [tok][k], 256B rows, swz (tok&15)<<4
  __shared__ __align__(16) unsigned short sB[128*128]; // Bt [n][k]
  const int tid = threadIdx.x;
  const int w = tid>>6, l = tid&63;
  const int m0 = blockIdx.x*128, nb = blockIdx.y*128;
  #pragma unroll
  for (int it=0; it<8; ++it){
    int task = it*256 + tid;
    int row = task>>4, ch = task&15;
    uint4 vv = *(const uint4*)(aout + (size_t)(m0+row)*128 + ch*8);
    *(uint4*)((char*)sA + row*256 + ((ch*16) ^ ((row&15)<<4))) = vv;
  }
  #pragma unroll
  for (int it=0; it<8; ++it){
    int task = it*256 + tid;
    int kp = task>>5, n4 = (task&31)*4;
    const float* wp = wproj + (size_t)(2*kp)*1024 + nb + n4;
    float4 wa = *(const float4*)wp;
    float4 wb = *(const float4*)(wp + 1024);
    unsigned int d0 = (unsigned int)f2bf(wa.x) | ((unsigned int)f2bf(wb.x)<<16);
    unsigned int d1 = (unsigned int)f2bf(wa.y) | ((unsigned int)f2bf(wb.y)<<16);
    unsigned int d2 = (unsigned int)f2bf(wa.z) | ((unsigned int)f2bf(wb.z)<<16);
    unsigned int d3 = (unsigned int)f2bf(wa.w) | ((unsigned int)f2bf(wb.w)<<16);
    int cb = kp*4;
    *(unsigned int*)((char*)sB + (size_t)(n4+0)*256 + (cb ^ (((n4+0)&15)<<4))) = d0;
    *(unsigned int*)((char*)sB + (size_t)(n4+1)*256 + (cb ^ (((n4+1)&15)<<4))) = d1;
    *(unsigned int*)((char*)sB + (size_t)(n4+2)*256 + (cb ^ (((n4+2)&15)<<4))) = d2;
    *(unsigned int*)((char*)sB + (size_t)(n4+3)*256 + (cb ^ (((n4+3)&15)<<4))) = d3;
  }
  __syncthreads();
  const int wm = (w>>1)*64, wn = (w&1)*64;
  f32x4 acc[4][4] = {};
  #pragma unroll
  for (int s=0; s<4; ++s){
    short8 af[4], bfr[4];
    #pragma unroll
    for (int i=0;i<4;i++){
      int row = wm + i*16 + (l&15);
      U16B ta; ta.u = *(const uint4*)((const char*)sA + row*256 + ((s*64 + (l>>4)*16) ^ ((row&15)<<4)));
      af[i] = ta.s;
      int col = wn + i*16 + (l&15);
      U16B tb; tb.u = *(const uint4*)((const char*)sB + col*256 + ((s*64 + (l>>4)*16) ^ ((col&15)<<4)));
      bfr[i] = tb.s;
    }
    #pragma unroll
    for (int i=0;i<4;i++)
      #pragma unroll
      for (int j=0;j<4;j++)
        acc[i][j] = __builtin_amdgcn_mfma_f32_16x16x32_bf16(af[i], bfr[j], acc[i][j], 0,0,0);
  }
  #pragma unroll
  for (int fn=0; fn<4; ++fn){
    int col = nb + wn + fn*16 + (l&15);
    float bv = bias[col];
    #pragma unroll
    for (int fm=0; fm<4; ++fm)
      #pragma unroll
      for (int i=0;i<4;i++)
        out[(size_t)(m0 + wm + fm*16 + (l>>4)*4 + i)*1024 + col] = acc[fm][fn][i] + bv;
  }
}

extern "C" void kernel_launch(void* const* d_in, const int* in_sizes, int n_in,
                              void* d_out, int out_size, void* d_ws, size_t ws_size,
                              hipStream_t stream){
  (void)in_sizes; (void)n_in; (void)out_size; (void)ws_size;
  const float* x     = (const float*)d_in[0];
  const float* gamma = (const float*)d_in[1];
  const float* beta  = (const float*)d_in[2];
  const float* wqkv  = (const float*)d_in[3];
  const float* wproj = (const float*)d_in[4];
  const float* bias  = (const float*)d_in[5];
  float* out = (float*)d_out;
  char* ws = (char*)d_ws;
  unsigned short* xn = (unsigned short*)ws;                                  // 32 MB
  unsigned short* q  = (unsigned short*)(ws + 33554432);                     // 4 MB
  unsigned short* kb = (unsigned short*)(ws + 33554432 + 4194304);           // 4 MB
  unsigned short* vT = (unsigned short*)(ws + 33554432 + 2*4194304);         // 4 MB
  unsigned short* ao = (unsigned short*)(ws + 33554432 + 3*4194304);         // 4 MB
  k_ln  <<<dim3(16384), dim3(256), 0, stream>>>(x, gamma, beta, xn);
  k_qkv <<<dim3(256,3), dim3(256), 0, stream>>>(xn, wqkv, q, kb, vT);
  k_attn<<<dim3(128,8), dim3(256), 0, stream>>>(q, kb, vT, ao);
  k_proj<<<dim3(128,8), dim3(256), 0, stream>>>(ao, wproj, bias, out);
}

// Round 2
// 112.779 us; speedup vs baseline: 1.2914x; 1.2914x over previous
//
#include <hip/hip_runtime.h>

// Dims: b=16, n=1024, EMB=1024, INNER=128, HEADS=8, HD=16
#define LOG2E 1.44269504088896340736f
#define QSCALE (0.08838834764831845f * LOG2E)   // INNER^-0.5 * log2(e)

using short8 = __attribute__((ext_vector_type(8))) short;
using f32x4  = __attribute__((ext_vector_type(4))) float;
using f32x16 = __attribute__((ext_vector_type(16))) float;

union U16B { uint4 u; short8 s; };

typedef __attribute__((address_space(3))) unsigned char lds_byte;
typedef const __attribute__((address_space(1))) unsigned char glb_byte;
#define GLOAD16(gp, lp) __builtin_amdgcn_global_load_lds((glb_byte*)(gp), (lds_byte*)(lp), 16, 0, 0)

static __device__ __forceinline__ unsigned short f2bf(float f){
  union { float f; unsigned int i; } c; c.f = f;
  unsigned int i = c.i;
  i += 0x7fffu + ((i >> 16) & 1u);   // RNE
  return (unsigned short)(i >> 16);
}

// ---------------- K0: weight convert/transpose (runs once per launch) ----------------
// wqkv [1024][384] f32 -> wqkvT [384][1024] bf16 (Q cols pre-scaled by QSCALE)
// wproj [128][1024] f32 -> wprojT [1024][128] bf16
__global__ __launch_bounds__(256) void k_cvtw(const float* __restrict__ wqkv,
                                              const float* __restrict__ wproj,
                                              unsigned short* __restrict__ wqkvT,
                                              unsigned short* __restrict__ wprojT){
  int t = blockIdx.x*256 + threadIdx.x;
  if (t < 49152){
    int n = t>>7, k0 = (t&127)*8;
    float sc = (n < 128) ? QSCALE : 1.0f;
    const float* src = wqkv + (size_t)k0*384 + n;
    ushort4 lo, hi;
    lo.x = f2bf(src[0]*sc);    lo.y = f2bf(src[384]*sc);
    lo.z = f2bf(src[768]*sc);  lo.w = f2bf(src[1152]*sc);
    hi.x = f2bf(src[1536]*sc); hi.y = f2bf(src[1920]*sc);
    hi.z = f2bf(src[2304]*sc); hi.w = f2bf(src[2688]*sc);
    *(ushort4*)(wqkvT + (size_t)n*1024 + k0)     = lo;
    *(ushort4*)(wqkvT + (size_t)n*1024 + k0 + 4) = hi;
  } else {
    int t2 = t - 49152;
    int n = t2>>4, k0 = (t2&15)*8;
    const float* src = wproj + (size_t)k0*1024 + n;
    ushort4 lo, hi;
    lo.x = f2bf(src[0]);    lo.y = f2bf(src[1024]);
    lo.z = f2bf(src[2048]); lo.w = f2bf(src[3072]);
    hi.x = f2bf(src[4096]); hi.y = f2bf(src[5120]);
    hi.z = f2bf(src[6144]); hi.w = f2bf(src[7168]);
    *(ushort4*)(wprojT + (size_t)n*128 + k0)     = lo;
    *(ushort4*)(wprojT + (size_t)n*128 + k0 + 4) = hi;
  }
}

// ---------------- K1: LayerNorm -> xn (bf16) ----------------
__global__ __launch_bounds__(256) void k_ln(const float* __restrict__ x,
                                            const float* __restrict__ gamma,
                                            const float* __restrict__ beta,
                                            unsigned short* __restrict__ xn){
  const int tok = blockIdx.x;
  const int tid = threadIdx.x;
  float4 v = ((const float4*)(x + (size_t)tok*1024))[tid];
  float s  = v.x+v.y+v.z+v.w;
  float s2 = v.x*v.x+v.y*v.y+v.z*v.z+v.w*v.w;
  #pragma unroll
  for (int o=32;o;o>>=1){ s += __shfl_xor(s,o); s2 += __shfl_xor(s2,o); }
  __shared__ float red[8];
  if ((tid&63)==0){ red[tid>>6] = s; red[4+(tid>>6)] = s2; }
  __syncthreads();
  s  = red[0]+red[1]+red[2]+red[3];
  s2 = red[4]+red[5]+red[6]+red[7];
  float mu   = s*(1.0f/1024.0f);
  float rstd = rsqrtf(s2*(1.0f/1024.0f) - mu*mu + 1e-5f);
  float4 g = ((const float4*)gamma)[tid];
  float4 b = ((const float4*)beta)[tid];
  ushort4 o;
  o.x = f2bf((v.x-mu)*rstd*g.x + b.x);
  o.y = f2bf((v.y-mu)*rstd*g.y + b.y);
  o.z = f2bf((v.z-mu)*rstd*g.z + b.z);
  o.w = f2bf((v.w-mu)*rstd*g.w + b.w);
  ((ushort4*)(xn + (size_t)tok*1024))[tid] = o;
}

// ---------------- K2: QKV GEMM (M=16384,K=1024,N=384), m97 structure ----------------
// grid (128 m-blocks, 3 sections): BM=128, BN=128, BK=64, 4 waves
__global__ __launch_bounds__(256) void k_qkv(const unsigned short* __restrict__ xn,
                                             const unsigned short* __restrict__ wT,
                                             unsigned short* __restrict__ q,
                                             unsigned short* __restrict__ kbuf,
                                             unsigned short* __restrict__ vT){
  __shared__ __align__(16) unsigned short sm[2*128*64]; // 32KB: A then Bt
  unsigned short* sA = sm;          // [128 tok][64 k], 128B rows, 16B-chunk XOR (row&7)<<4
  unsigned short* sB = sm + 8192;   // [128 n][64 k], same swizzle
  const int tid = threadIdx.x;
  const int w = tid>>6, l = tid&63;
  const int m0 = blockIdx.x*128;
  const int sec = blockIdx.y;
  const int nb = sec*128;
  const int wm = (w>>1)*64, wn = (w&1)*64;
  f32x4 acc[4][4] = {};
  for (int k0=0; k0<1024; k0+=64){
    // stage A: linear LDS dest, inverse-swizzled global source
    #pragma unroll
    for (int i=0;i<4;i++){
      int chunk = i*256 + tid;
      int row = chunk>>3;
      int ch = (tid&7) ^ (row&7);
      GLOAD16(xn + (size_t)(m0+row)*1024 + k0 + ch*8,
              (char*)sA + (i*256 + w*64)*16);
    }
    #pragma unroll
    for (int i=0;i<4;i++){
      int chunk = i*256 + tid;
      int row = chunk>>3;
      int ch = (tid&7) ^ (row&7);
      GLOAD16(wT + (size_t)(nb+row)*1024 + k0 + ch*8,
              (char*)sB + (i*256 + w*64)*16);
    }
    __syncthreads();
    #pragma unroll
    for (int s=0; s<2; ++s){
      short8 af[4], bfr[4];
      #pragma unroll
      for (int i=0;i<4;i++){
        int row = wm + i*16 + (l&15);
        U16B ta; ta.u = *(const uint4*)((const char*)sA + row*128 + ((s*64 + (l>>4)*16) ^ ((row&7)<<4)));
        af[i] = ta.s;
        int col = wn + i*16 + (l&15);
        U16B tb; tb.u = *(const uint4*)((const char*)sB + col*128 + ((s*64 + (l>>4)*16) ^ ((col&7)<<4)));
        bfr[i] = tb.s;
      }
      #pragma unroll
      for (int i=0;i<4;i++)
        #pragma unroll
        for (int j=0;j<4;j++)
          acc[i][j] = __builtin_amdgcn_mfma_f32_16x16x32_bf16(af[i], bfr[j], acc[i][j], 0,0,0);
    }
    __syncthreads();
  }
  // Epilogue: re-layout via LDS (reuse all 32KB), write head-major buffers
  const int b  = m0 >> 10;
  const int n0 = m0 & 1023;
  if (sec < 2){
    // LDS [128 tok][128 f] ushort, 256B rows, 16B-chunk XOR (tok&15)<<4
    #pragma unroll
    for (int fm=0; fm<4; ++fm)
      #pragma unroll
      for (int fn=0; fn<4; ++fn){
        int colf = wn + fn*16 + (l&15);
        #pragma unroll
        for (int i=0;i<4;i++){
          int row = wm + fm*16 + (l>>4)*4 + i;
          *(unsigned short*)((char*)sm + row*256 + ((2*colf) ^ ((row&15)<<4))) = f2bf(acc[fm][fn][i]);
        }
      }
    __syncthreads();
    unsigned short* dst = (sec==0) ? q : kbuf;
    #pragma unroll
    for (int it=0; it<8; ++it){
      int chunk = it*256 + tid;          // 128 rows x 16 chunks
      int tokl = chunk>>4, cc = chunk&15;
      uint4 vv = *(const uint4*)((const char*)sm + tokl*256 + ((cc*16) ^ ((tokl&15)<<4)));
      int h = cc>>1, d0 = (cc&1)*8;
      *(uint4*)(dst + ((size_t)(b*8 + h)*1024 + n0 + tokl)*16 + d0) = vv;
    }
  } else {
    // v transposed: LDS [128 f][128 tok] ushort, 256B rows, XOR (f&15)<<4
    #pragma unroll
    for (int fm=0; fm<4; ++fm)
      #pragma unroll
      for (int fn=0; fn<4; ++fn){
        int colf = wn + fn*16 + (l&15);      // feature
        int r0 = wm + fm*16 + (l>>4)*4;      // token base
        ushort4 pk;
        pk.x = f2bf(acc[fm][fn][0]); pk.y = f2bf(acc[fm][fn][1]);
        pk.z = f2bf(acc[fm][fn][2]); pk.w = f2bf(acc[fm][fn][3]);
        *(ushort4*)((char*)sm + colf*256 + ((2*r0) ^ ((colf&15)<<4))) = pk;
      }
    __syncthreads();
    #pragma unroll
    for (int it=0; it<8; ++it){
      int chunk = it*256 + tid;          // 128 f x 16 chunks
      int f = chunk>>4, cc = chunk&15;
      uint4 vv = *(const uint4*)((const char*)sm + f*256 + ((cc*16) ^ ((f&15)<<4)));
      int h = f>>4, d = f&15;
      *(uint4*)(vT + ((size_t)(b*8 + h)*16 + d)*1024 + n0 + cc*8) = vv;
    }
  }
}

// ---------------- K3: flash attention (swapped QK^T, lane-local softmax) ----------------
// grid (128 bh, 8 qchunk), 4 waves x 32 q-rows
__global__ __launch_bounds__(256) void k_attn(const unsigned short* __restrict__ q,
                                              const unsigned short* __restrict__ kbuf,
                                              const unsigned short* __restrict__ vT,
                                              unsigned short* __restrict__ aout){
  const int bh = blockIdx.x;
  const int qc = blockIdx.y;
  const int w = threadIdx.x>>6, l = threadIdx.x&63;
  const int l31 = l&31, hi = l>>5;
  const int h = bh & 7;
  const int qrow = qc*128 + w*32 + l31;
  U16B qf_u; qf_u.u = *(const uint4*)(q + ((size_t)bh*1024 + qrow)*16 + hi*8);
  const short8 qf = qf_u.s;
  const unsigned short* kp0 = kbuf + (size_t)bh*1024*16;
  const unsigned short* vp0 = vT + (size_t)bh*16*1024;
  const bool vok = (l31 < 16);
  const unsigned short* vrow = vp0 + (size_t)(l31 & 15)*1024;
  f32x16 acc = {};
  float m = -1e30f, ssum = 0.0f;
  for (int t=0; t<32; ++t){
    U16B kf_u; kf_u.u = *(const uint4*)(kp0 + (size_t)(t*32 + l31)*16 + hi*8);
    f32x16 zz = {};
    f32x16 sv = __builtin_amdgcn_mfma_f32_32x32x16_bf16(kf_u.s, qf, zz, 0,0,0);
    float tm = sv[0];
    #pragma unroll
    for (int r=1;r<16;r++) tm = fmaxf(tm, sv[r]);
    tm = fmaxf(tm, __shfl_xor(tm, 32));
    float mnew = fmaxf(m, tm);
    float sc = __builtin_amdgcn_exp2f(m - mnew);
    m = mnew;
    ssum *= sc;
    #pragma unroll
    for (int r=0;r<16;r++) acc[r] *= sc;
    float p[16];
    #pragma unroll
    for (int r=0;r<16;r++){ p[r] = __builtin_amdgcn_exp2f(sv[r] - m); ssum += p[r]; }
    unsigned int u[8];
    #pragma unroll
    for (int j=0;j<8;j++){
      asm("v_cvt_pk_bf16_f32 %0, %1, %2" : "=v"(u[j]) : "v"(p[2*j]), "v"(p[2*j+1]));
    }
    unsigned int x0 = __shfl_xor(u[0],32), x1 = __shfl_xor(u[1],32);
    unsigned int x2 = __shfl_xor(u[2],32), x3 = __shfl_xor(u[3],32);
    U16B p0;
    p0.u.x = hi ? x2 : u[0];
    p0.u.y = hi ? x3 : u[1];
    p0.u.z = hi ? u[2] : x0;
    p0.u.w = hi ? u[3] : x1;
    unsigned int x4 = __shfl_xor(u[4],32), x5 = __shfl_xor(u[5],32);
    unsigned int x6 = __shfl_xor(u[6],32), x7 = __shfl_xor(u[7],32);
    U16B p1;
    p1.u.x = hi ? x6 : u[4];
    p1.u.y = hi ? x7 : u[5];
    p1.u.z = hi ? u[6] : x4;
    p1.u.w = hi ? u[7] : x5;
    U16B v0, v1;
    v0.u = make_uint4(0,0,0,0); v1.u = make_uint4(0,0,0,0);
    if (vok){
      v0.u = *(const uint4*)(vrow + (size_t)t*32 + hi*8);
      v1.u = *(const uint4*)(vrow + (size_t)t*32 + 16 + hi*8);
    }
    acc = __builtin_amdgcn_mfma_f32_32x32x16_bf16(v0.s, p0.s, acc, 0,0,0);
    acc = __builtin_amdgcn_mfma_f32_32x32x16_bf16(v1.s, p1.s, acc, 0,0,0);
  }
  ssum += __shfl_xor(ssum, 32);
  float inv = 1.0f/ssum;
  const size_t tok = (size_t)(bh>>3)*1024 + qrow;
  ushort4 o;
  o.x = f2bf(acc[0]*inv); o.y = f2bf(acc[1]*inv); o.z = f2bf(acc[2]*inv); o.w = f2bf(acc[3]*inv);
  *(ushort4*)(aout + tok*128 + h*16 + hi*4) = o;
  o.x = f2bf(acc[4]*inv); o.y = f2bf(acc[5]*inv); o.z = f2bf(acc[6]*inv); o.w = f2bf(acc[7]*inv);
  *(ushort4*)(aout + tok*128 + h*16 + 8 + hi*4) = o;
}

// ---------------- K4: out-projection (M=16384,K=128,N=1024) + bias ----------------
// grid (128, 8); K=128 single LDS stage via global_load_lds
__global__ __launch_bounds__(256) void k_proj(const unsigned short* __restrict__ aout,
                                              const unsigned short* __restrict__ wT, // [1024 n][128 k]
                                              const float* __restrict__ bias,
                                              float* __restrict__ out){
  __shared__ __align__(16) unsigned short sA[128*128]; // [tok][k], 256B rows, XOR (row&15)<<4
  __shared__ __align__(16) unsigned short sB[128*128]; // [n][k], same
  const int tid = threadIdx.x;
  const int w = tid>>6, l = tid&63;
  const int m0 = blockIdx.x*128, nb = blockIdx.y*128;
  #pragma unroll
  for (int i=0;i<8;i++){
    int chunk = i*256 + tid;
    int row = chunk>>4;
    int ch = (tid&15) ^ (row&15);
    GLOAD16(aout + (size_t)(m0+row)*128 + ch*8, (char*)sA + (i*256 + w*64)*16);
  }
  #pragma unroll
  for (int i=0;i<8;i++){
    int chunk = i*256 + tid;
    int row = chunk>>4;
    int ch = (tid&15) ^ (row&15);
    GLOAD16(wT + (size_t)(nb+row)*128 + ch*8, (char*)sB + (i*256 + w*64)*16);
  }
  __syncthreads();
  const int wm = (w>>1)*64, wn = (w&1)*64;
  f32x4 acc[4][4] = {};
  #pragma unroll
  for (int s=0; s<4; ++s){
    short8 af[4], bfr[4];
    #pragma unroll
    for (int i=0;i<4;i++){
      int row = wm + i*16 + (l&15);
      U16B ta; ta.u = *(const uint4*)((const char*)sA + row*256 + ((s*64 + (l>>4)*16) ^ ((row&15)<<4)));
      af[i] = ta.s;
      int col = wn + i*16 + (l&15);
      U16B tb; tb.u = *(const uint4*)((const char*)sB + col*256 + ((s*64 + (l>>4)*16) ^ ((col&15)<<4)));
      bfr[i] = tb.s;
    }
    #pragma unroll
    for (int i=0;i<4;i++)
      #pragma unroll
      for (int j=0;j<4;j++)
        acc[i][j] = __builtin_amdgcn_mfma_f32_16x16x32_bf16(af[i], bfr[j], acc[i][j], 0,0,0);
  }
  #pragma unroll
  for (int fn=0; fn<4; ++fn){
    int col = nb + wn + fn*16 + (l&15);
    float bv = bias[col];
    #pragma unroll
    for (int fm=0; fm<4; ++fm)
      #pragma unroll
      for (int i=0;i<4;i++)
        out[(size_t)(m0 + wm + fm*16 + (l>>4)*4 + i)*1024 + col] = acc[fm][fn][i] + bv;
  }
}

extern "C" void kernel_launch(void* const* d_in, const int* in_sizes, int n_in,
                              void* d_out, int out_size, void* d_ws, size_t ws_size,
                              hipStream_t stream){
  (void)in_sizes; (void)n_in; (void)out_size; (void)ws_size;
  const float* x     = (const float*)d_in[0];
  const float* gamma = (const float*)d_in[1];
  const float* beta  = (const float*)d_in[2];
  const float* wqkv  = (const float*)d_in[3];
  const float* wproj = (const float*)d_in[4];
  const float* bias  = (const float*)d_in[5];
  float* out = (float*)d_out;
  char* ws = (char*)d_ws;
  unsigned short* xn = (unsigned short*)ws;                                  // 32 MB
  unsigned short* q  = (unsigned short*)(ws + 33554432);                     // 4 MB
  unsigned short* kb = (unsigned short*)(ws + 33554432 + 4194304);           // 4 MB
  unsigned short* vT = (unsigned short*)(ws + 33554432 + 2*4194304);         // 4 MB
  unsigned short* ao = (unsigned short*)(ws + 33554432 + 3*4194304);         // 4 MB
  unsigned short* wqkvT = (unsigned short*)(ws + 33554432 + 4*4194304);      // 768 KB
  unsigned short* wprojT = (unsigned short*)(ws + 33554432 + 4*4194304 + 786432); // 256 KB
  k_cvtw<<<dim3(256), dim3(256), 0, stream>>>(wqkv, wproj, wqkvT, wprojT);
  k_ln  <<<dim3(16384), dim3(256), 0, stream>>>(x, gamma, beta, xn);
  k_qkv <<<dim3(128,3), dim3(256), 0, stream>>>(xn, wqkvT, q, kb, vT);
  k_attn<<<dim3(128,8), dim3(256), 0, stream>>>(q, kb, vT, ao);
  k_proj<<<dim3(128,8), dim3(256), 0, stream>>>(ao, wprojT, bias, out);
}

// Round 3
// 103.180 us; speedup vs baseline: 1.4115x; 1.0930x over previous
//
#include <hip/hip_runtime.h>

// Dims: b=16, n=1024, EMB=1024, INNER=128, HEADS=8, HD=16
#define LOG2E 1.44269504088896340736f
#define QSCALE (0.08838834764831845f * LOG2E)   // INNER^-0.5 * log2(e)

using short8 = __attribute__((ext_vector_type(8))) short;
using f32x4  = __attribute__((ext_vector_type(4))) float;
using f32x16 = __attribute__((ext_vector_type(16))) float;

union U16B { uint4 u; short8 s; };

typedef __attribute__((address_space(3))) unsigned char lds_byte;
typedef const __attribute__((address_space(1))) unsigned char glb_byte;
#define GLOAD16(gp, lp) __builtin_amdgcn_global_load_lds((glb_byte*)(gp), (lds_byte*)(lp), 16, 0, 0)

static __device__ __forceinline__ unsigned short f2bf(float f){
  union { float f; unsigned int i; } c; c.f = f;
  unsigned int i = c.i;
  i += 0x7fffu + ((i >> 16) & 1u);   // RNE
  return (unsigned short)(i >> 16);
}

// ---------------- K0: weight convert/transpose (runs once per launch) ----------------
__global__ __launch_bounds__(256) void k_cvtw(const float* __restrict__ wqkv,
                                              const float* __restrict__ wproj,
                                              unsigned short* __restrict__ wqkvT,
                                              unsigned short* __restrict__ wprojT){
  int t = blockIdx.x*256 + threadIdx.x;
  if (t < 49152){
    int n = t>>7, k0 = (t&127)*8;
    float sc = (n < 128) ? QSCALE : 1.0f;
    const float* src = wqkv + (size_t)k0*384 + n;
    ushort4 lo, hi;
    lo.x = f2bf(src[0]*sc);    lo.y = f2bf(src[384]*sc);
    lo.z = f2bf(src[768]*sc);  lo.w = f2bf(src[1152]*sc);
    hi.x = f2bf(src[1536]*sc); hi.y = f2bf(src[1920]*sc);
    hi.z = f2bf(src[2304]*sc); hi.w = f2bf(src[2688]*sc);
    *(ushort4*)(wqkvT + (size_t)n*1024 + k0)     = lo;
    *(ushort4*)(wqkvT + (size_t)n*1024 + k0 + 4) = hi;
  } else {
    int t2 = t - 49152;
    int n = t2>>4, k0 = (t2&15)*8;
    const float* src = wproj + (size_t)k0*1024 + n;
    ushort4 lo, hi;
    lo.x = f2bf(src[0]);    lo.y = f2bf(src[1024]);
    lo.z = f2bf(src[2048]); lo.w = f2bf(src[3072]);
    hi.x = f2bf(src[4096]); hi.y = f2bf(src[5120]);
    hi.z = f2bf(src[6144]); hi.w = f2bf(src[7168]);
    *(ushort4*)(wprojT + (size_t)n*128 + k0)     = lo;
    *(ushort4*)(wprojT + (size_t)n*128 + k0 + 4) = hi;
  }
}

// ---------------- K1: LayerNorm -> xn (bf16), one wave per token ----------------
__global__ __launch_bounds__(256) void k_ln(const float* __restrict__ x,
                                            const float* __restrict__ gamma,
                                            const float* __restrict__ beta,
                                            unsigned short* __restrict__ xn){
  const int tok = (blockIdx.x*256 + threadIdx.x) >> 6;
  const int l = threadIdx.x & 63;
  const float4* xr = (const float4*)(x + (size_t)tok*1024);
  float4 v[4];
  #pragma unroll
  for (int i=0;i<4;i++) v[i] = xr[l + i*64];
  float s = 0.f, s2 = 0.f;
  #pragma unroll
  for (int i=0;i<4;i++){
    s  += v[i].x+v[i].y+v[i].z+v[i].w;
    s2 += v[i].x*v[i].x+v[i].y*v[i].y+v[i].z*v[i].z+v[i].w*v[i].w;
  }
  #pragma unroll
  for (int o=32;o;o>>=1){ s += __shfl_xor(s,o); s2 += __shfl_xor(s2,o); }
  float mu   = s*(1.0f/1024.0f);
  float rstd = rsqrtf(s2*(1.0f/1024.0f) - mu*mu + 1e-5f);
  ushort4* xo = (ushort4*)(xn + (size_t)tok*1024);
  #pragma unroll
  for (int i=0;i<4;i++){
    float4 g = ((const float4*)gamma)[l + i*64];
    float4 b = ((const float4*)beta)[l + i*64];
    ushort4 o;
    o.x = f2bf((v[i].x-mu)*rstd*g.x + b.x);
    o.y = f2bf((v[i].y-mu)*rstd*g.y + b.y);
    o.z = f2bf((v[i].z-mu)*rstd*g.z + b.z);
    o.w = f2bf((v[i].w-mu)*rstd*g.w + b.w);
    xo[l + i*64] = o;
  }
}

// ---------------- K2: QKV GEMM (M=16384,K=1024,N=384), BM=64 BN=128 BK=64 ----------------
// grid (256 m-blocks, 3 sections), 4 waves
__global__ __launch_bounds__(256) void k_qkv(const unsigned short* __restrict__ xn,
                                             const unsigned short* __restrict__ wT,
                                             unsigned short* __restrict__ q,
                                             unsigned short* __restrict__ kbuf,
                                             unsigned short* __restrict__ vT){
  __shared__ __align__(16) unsigned short sm[64*64 + 128*64]; // 24KB
  unsigned short* sA = sm;          // [64 tok][64 k], 128B rows, 16B-chunk XOR (row&7)<<4
  unsigned short* sB = sm + 4096;   // [128 n][64 k], same swizzle
  const int tid = threadIdx.x;
  const int w = tid>>6, l = tid&63;
  const int m0 = blockIdx.x*64;
  const int sec = blockIdx.y;
  const int nb = sec*128;
  const int wm = (w>>1)*32, wn = (w&1)*64;
  f32x4 acc[2][4] = {};
  for (int k0=0; k0<1024; k0+=64){
    #pragma unroll
    for (int i=0;i<2;i++){
      int chunk = i*256 + tid;
      int row = chunk>>3;
      int ch = (tid&7) ^ (row&7);
      GLOAD16(xn + (size_t)(m0+row)*1024 + k0 + ch*8,
              (char*)sA + (i*256 + w*64)*16);
    }
    #pragma unroll
    for (int i=0;i<4;i++){
      int chunk = i*256 + tid;
      int row = chunk>>3;
      int ch = (tid&7) ^ (row&7);
      GLOAD16(wT + (size_t)(nb+row)*1024 + k0 + ch*8,
              (char*)sB + (i*256 + w*64)*16);
    }
    __syncthreads();
    #pragma unroll
    for (int s=0; s<2; ++s){
      short8 af[2], bfr[4];
      #pragma unroll
      for (int i=0;i<2;i++){
        int row = wm + i*16 + (l&15);
        U16B ta; ta.u = *(const uint4*)((const char*)sA + row*128 + ((s*64 + (l>>4)*16) ^ ((row&7)<<4)));
        af[i] = ta.s;
      }
      #pragma unroll
      for (int j=0;j<4;j++){
        int col = wn + j*16 + (l&15);
        U16B tb; tb.u = *(const uint4*)((const char*)sB + col*128 + ((s*64 + (l>>4)*16) ^ ((col&7)<<4)));
        bfr[j] = tb.s;
      }
      #pragma unroll
      for (int i=0;i<2;i++)
        #pragma unroll
        for (int j=0;j<4;j++)
          acc[i][j] = __builtin_amdgcn_mfma_f32_16x16x32_bf16(af[i], bfr[j], acc[i][j], 0,0,0);
    }
    __syncthreads();
  }
  const int b  = m0 >> 10;
  const int n0 = m0 & 1023;
  if (sec < 2){
    // LDS [64 tok][128 f] ushort, 256B rows, 16B-chunk XOR (tok&15)<<4
    #pragma unroll
    for (int fm=0; fm<2; ++fm)
      #pragma unroll
      for (int fn=0; fn<4; ++fn){
        int colf = wn + fn*16 + (l&15);
        #pragma unroll
        for (int i=0;i<4;i++){
          int row = wm + fm*16 + (l>>4)*4 + i;
          *(unsigned short*)((char*)sm + row*256 + ((2*colf) ^ ((row&15)<<4))) = f2bf(acc[fm][fn][i]);
        }
      }
    __syncthreads();
    unsigned short* dst = (sec==0) ? q : kbuf;
    #pragma unroll
    for (int it=0; it<4; ++it){
      int chunk = it*256 + tid;          // 64 rows x 16 chunks
      int tokl = chunk>>4, cc = chunk&15;
      uint4 vv = *(const uint4*)((const char*)sm + tokl*256 + ((cc*16) ^ ((tokl&15)<<4)));
      int h = cc>>1, d0 = (cc&1)*8;
      *(uint4*)(dst + ((size_t)(b*8 + h)*1024 + n0 + tokl)*16 + d0) = vv;
    }
  } else {
    // vT with token bits2<->3 swapped within each 16-group (so attn PV needs no lane weave)
    // LDS [128 f][64 tok] ushort, 128B rows, XOR (f&7)<<4
    #pragma unroll
    for (int fm=0; fm<2; ++fm)
      #pragma unroll
      for (int fn=0; fn<4; ++fn){
        int colf = wn + fn*16 + (l&15);
        int r0 = wm + fm*16 + (l>>4)*4;
        ushort4 pk;
        pk.x = f2bf(acc[fm][fn][0]); pk.y = f2bf(acc[fm][fn][1]);
        pk.z = f2bf(acc[fm][fn][2]); pk.w = f2bf(acc[fm][fn][3]);
        *(ushort4*)((char*)sm + colf*128 + ((2*r0) ^ ((colf&7)<<4))) = pk;
      }
    __syncthreads();
    #pragma unroll
    for (int it=0; it<4; ++it){
      int chunk = it*256 + tid;          // 128 f x 8 chunks
      int f = chunk>>3, cc = chunk&7;
      uint4 vv = *(const uint4*)((const char*)sm + f*128 + ((cc*16) ^ ((f&7)<<4)));
      int h = f>>4, d = f&15;
      // tokens cc*8..cc*8+7 -> permuted positions (swap bit2<->bit3)
      unsigned short* dp = vT + ((size_t)(b*8 + h)*16 + d)*1024 + n0 + (cc>>1)*16 + (cc&1)*4;
      *(uint2*)dp       = make_uint2(vv.x, vv.y);
      *(uint2*)(dp + 8) = make_uint2(vv.z, vv.w);
    }
  }
}

// ---------------- K3: flash attention (swapped QK^T, weave-free PV, defer-max) ----------------
// grid (128 bh, 8 qchunk), 4 waves x 32 q-rows
__global__ __launch_bounds__(256) void k_attn(const unsigned short* __restrict__ q,
                                              const unsigned short* __restrict__ kbuf,
                                              const unsigned short* __restrict__ vT,
                                              unsigned short* __restrict__ aout){
  const int bh = blockIdx.x;
  const int qc = blockIdx.y;
  const int w = threadIdx.x>>6, l = threadIdx.x&63;
  const int l31 = l&31, hi = l>>5;
  const int h = bh & 7;
  const int qrow = qc*128 + w*32 + l31;
  U16B qf_u; qf_u.u = *(const uint4*)(q + ((size_t)bh*1024 + qrow)*16 + hi*8);
  const short8 qf = qf_u.s;
  const unsigned short* kp0 = kbuf + (size_t)bh*1024*16;
  const unsigned short* vrow = vT + (size_t)bh*16*1024 + (size_t)(l31 & 15)*1024;
  const bool vok = (l31 < 16);
  f32x16 acc = {};
  float m = -1e30f, ssum = 0.0f;
  U16B kf; kf.u = *(const uint4*)(kp0 + (size_t)l31*16 + hi*8);
  for (int t=0; t<32; ++t){
    // prefetch next K tile (wraps at t=31; value unused next launch anyway)
    U16B kn; kn.u = *(const uint4*)(kp0 + (size_t)((((t+1)&31))*32 + l31)*16 + hi*8);
    // V loads issued early (consumed after softmax)
    U16B v0, v1;
    v0.u = make_uint4(0,0,0,0); v1.u = make_uint4(0,0,0,0);
    if (vok){
      v0.u = *(const uint4*)(vrow + (size_t)t*32 + hi*8);
      v1.u = *(const uint4*)(vrow + (size_t)t*32 + 16 + hi*8);
    }
    f32x16 zz = {};
    f32x16 sv = __builtin_amdgcn_mfma_f32_32x32x16_bf16(kf.s, qf, zz, 0,0,0);
    // max over 16 lane-local scores (max3-friendly tree) + cross-half
    float a0 = fmaxf(fmaxf(sv[0],sv[1]),sv[2]);
    float a1 = fmaxf(fmaxf(sv[3],sv[4]),sv[5]);
    float a2 = fmaxf(fmaxf(sv[6],sv[7]),sv[8]);
    float a3 = fmaxf(fmaxf(sv[9],sv[10]),sv[11]);
    float a4 = fmaxf(fmaxf(sv[12],sv[13]),sv[14]);
    float tm = fmaxf(fmaxf(fmaxf(a0,a1),a2), fmaxf(fmaxf(a3,a4),sv[15]));
    tm = fmaxf(tm, __shfl_xor(tm, 32));
    // defer-max: rescale only when max grows by >8 (exp2 domain; P bounded by 256)
    if (__any(tm > m + 8.0f)){
      float mnew = fmaxf(m, tm);
      float sc = __builtin_amdgcn_exp2f(m - mnew);
      m = mnew;
      ssum *= sc;
      #pragma unroll
      for (int r=0;r<8;r++) acc[r] *= sc;   // acc[8..15] structurally 0
    }
    float p[16];
    #pragma unroll
    for (int r=0;r<16;r++){ p[r] = __builtin_amdgcn_exp2f(sv[r] - m); }
    float t0=0.f,t1=0.f,t2=0.f,t3=0.f;
    #pragma unroll
    for (int r=0;r<4;r++){ t0+=p[r]; t1+=p[4+r]; t2+=p[8+r]; t3+=p[12+r]; }
    ssum += (t0+t1) + (t2+t3);
    unsigned int u[8];
    #pragma unroll
    for (int j=0;j<8;j++){
      asm("v_cvt_pk_bf16_f32 %0, %1, %2" : "=v"(u[j]) : "v"(p[2*j]), "v"(p[2*j+1]));
    }
    // vT token-permuted storage makes register order == B-fragment order: no weave
    U16B p0, p1;
    p0.u.x = u[0]; p0.u.y = u[1]; p0.u.z = u[2]; p0.u.w = u[3];
    p1.u.x = u[4]; p1.u.y = u[5]; p1.u.z = u[6]; p1.u.w = u[7];
    acc = __builtin_amdgcn_mfma_f32_32x32x16_bf16(v0.s, p0.s, acc, 0,0,0);
    acc = __builtin_amdgcn_mfma_f32_32x32x16_bf16(v1.s, p1.s, acc, 0,0,0);
    kf = kn;
  }
  ssum += __shfl_xor(ssum, 32);
  float inv = 1.0f/ssum;
  const size_t tok = (size_t)(bh>>3)*1024 + qrow;
  ushort4 o;
  o.x = f2bf(acc[0]*inv); o.y = f2bf(acc[1]*inv); o.z = f2bf(acc[2]*inv); o.w = f2bf(acc[3]*inv);
  *(ushort4*)(aout + tok*128 + h*16 + hi*4) = o;
  o.x = f2bf(acc[4]*inv); o.y = f2bf(acc[5]*inv); o.z = f2bf(acc[6]*inv); o.w = f2bf(acc[7]*inv);
  *(ushort4*)(aout + tok*128 + h*16 + 8 + hi*4) = o;
}

// ---------------- K4: out-projection (M=16384,K=128,N=1024) + bias ----------------
__global__ __launch_bounds__(256) void k_proj(const unsigned short* __restrict__ aout,
                                              const unsigned short* __restrict__ wT, // [1024 n][128 k]
                                              const float* __restrict__ bias,
                                              float* __restrict__ out){
  __shared__ __align__(16) unsigned short sA[128*128]; // [tok][k], 256B rows, XOR (row&15)<<4
  __shared__ __align__(16) unsigned short sB[128*128]; // [n][k], same
  const int tid = threadIdx.x;
  const int w = tid>>6, l = tid&63;
  const int m0 = blockIdx.x*128, nb = blockIdx.y*128;
  #pragma unroll
  for (int i=0;i<8;i++){
    int chunk = i*256 + tid;
    int row = chunk>>4;
    int ch = (tid&15) ^ (row&15);
    GLOAD16(aout + (size_t)(m0+row)*128 + ch*8, (char*)sA + (i*256 + w*64)*16);
  }
  #pragma unroll
  for (int i=0;i<8;i++){
    int chunk = i*256 + tid;
    int row = chunk>>4;
    int ch = (tid&15) ^ (row&15);
    GLOAD16(wT + (size_t)(nb+row)*128 + ch*8, (char*)sB + (i*256 + w*64)*16);
  }
  __syncthreads();
  const int wm = (w>>1)*64, wn = (w&1)*64;
  f32x4 acc[4][4] = {};
  #pragma unroll
  for (int s=0; s<4; ++s){
    short8 af[4], bfr[4];
    #pragma unroll
    for (int i=0;i<4;i++){
      int row = wm + i*16 + (l&15);
      U16B ta; ta.u = *(const uint4*)((const char*)sA + row*256 + ((s*64 + (l>>4)*16) ^ ((row&15)<<4)));
      af[i] = ta.s;
      int col = wn + i*16 + (l&15);
      U16B tb; tb.u = *(const uint4*)((const char*)sB + col*256 + ((s*64 + (l>>4)*16) ^ ((col&15)<<4)));
      bfr[i] = tb.s;
    }
    #pragma unroll
    for (int i=0;i<4;i++)
      #pragma unroll
      for (int j=0;j<4;j++)
        acc[i][j] = __builtin_amdgcn_mfma_f32_16x16x32_bf16(af[i], bfr[j], acc[i][j], 0,0,0);
  }
  #pragma unroll
  for (int fn=0; fn<4; ++fn){
    int col = nb + wn + fn*16 + (l&15);
    float bv = bias[col];
    #pragma unroll
    for (int fm=0; fm<4; ++fm)
      #pragma unroll
      for (int i=0;i<4;i++)
        out[(size_t)(m0 + wm + fm*16 + (l>>4)*4 + i)*1024 + col] = acc[fm][fn][i] + bv;
  }
}

extern "C" void kernel_launch(void* const* d_in, const int* in_sizes, int n_in,
                              void* d_out, int out_size, void* d_ws, size_t ws_size,
                              hipStream_t stream){
  (void)in_sizes; (void)n_in; (void)out_size; (void)ws_size;
  const float* x     = (const float*)d_in[0];
  const float* gamma = (const float*)d_in[1];
  const float* beta  = (const float*)d_in[2];
  const float* wqkv  = (const float*)d_in[3];
  const float* wproj = (const float*)d_in[4];
  const float* bias  = (const float*)d_in[5];
  float* out = (float*)d_out;
  char* ws = (char*)d_ws;
  unsigned short* xn = (unsigned short*)ws;                                  // 32 MB
  unsigned short* q  = (unsigned short*)(ws + 33554432);                     // 4 MB
  unsigned short* kb = (unsigned short*)(ws + 33554432 + 4194304);           // 4 MB
  unsigned short* vT = (unsigned short*)(ws + 33554432 + 2*4194304);         // 4 MB
  unsigned short* ao = (unsigned short*)(ws + 33554432 + 3*4194304);         // 4 MB
  unsigned short* wqkvT = (unsigned short*)(ws + 33554432 + 4*4194304);      // 768 KB
  unsigned short* wprojT = (unsigned short*)(ws + 33554432 + 4*4194304 + 786432); // 256 KB
  k_cvtw<<<dim3(256), dim3(256), 0, stream>>>(wqkv, wproj, wqkvT, wprojT);
  k_ln  <<<dim3(4096), dim3(256), 0, stream>>>(x, gamma, beta, xn);
  k_qkv <<<dim3(256,3), dim3(256), 0, stream>>>(xn, wqkvT, q, kb, vT);
  k_attn<<<dim3(128,8), dim3(256), 0, stream>>>(q, kb, vT, ao);
  k_proj<<<dim3(128,8), dim3(256), 0, stream>>>(ao, wprojT, bias, out);
}

// Round 4
// 91.816 us; speedup vs baseline: 1.5862x; 1.1238x over previous
//
#include <hip/hip_runtime.h>

// Dims: b=16, n=1024, EMB=1024, INNER=128, HEADS=8, HD=16
#define LOG2E 1.44269504088896340736f
#define QSCALE (0.08838834764831845f * LOG2E)   // INNER^-0.5 * log2(e)

using short8 = __attribute__((ext_vector_type(8))) short;
using f32x4  = __attribute__((ext_vector_type(4))) float;
using f32x16 = __attribute__((ext_vector_type(16))) float;

union U16B { uint4 u; short8 s; };

typedef __attribute__((address_space(3))) unsigned char lds_byte;
typedef const __attribute__((address_space(1))) unsigned char glb_byte;
#define GLOAD16(gp, lp) __builtin_amdgcn_global_load_lds((glb_byte*)(gp), (lds_byte*)(lp), 16, 0, 0)

static __device__ __forceinline__ unsigned short f2bf(float f){
  union { float f; unsigned int i; } c; c.f = f;
  unsigned int i = c.i;
  i += 0x7fffu + ((i >> 16) & 1u);   // RNE
  return (unsigned short)(i >> 16);
}

// ---------------- K0: weight convert/transpose (runs once per launch) ----------------
__global__ __launch_bounds__(256) void k_cvtw(const float* __restrict__ wqkv,
                                              const float* __restrict__ wproj,
                                              unsigned short* __restrict__ wqkvT,
                                              unsigned short* __restrict__ wprojT){
  int t = blockIdx.x*256 + threadIdx.x;
  if (t < 49152){
    int n = t>>7, k0 = (t&127)*8;
    float sc = (n < 128) ? QSCALE : 1.0f;
    const float* src = wqkv + (size_t)k0*384 + n;
    ushort4 lo, hi;
    lo.x = f2bf(src[0]*sc);    lo.y = f2bf(src[384]*sc);
    lo.z = f2bf(src[768]*sc);  lo.w = f2bf(src[1152]*sc);
    hi.x = f2bf(src[1536]*sc); hi.y = f2bf(src[1920]*sc);
    hi.z = f2bf(src[2304]*sc); hi.w = f2bf(src[2688]*sc);
    *(ushort4*)(wqkvT + (size_t)n*1024 + k0)     = lo;
    *(ushort4*)(wqkvT + (size_t)n*1024 + k0 + 4) = hi;
  } else {
    int t2 = t - 49152;
    int n = t2>>4, k0 = (t2&15)*8;
    const float* src = wproj + (size_t)k0*1024 + n;
    ushort4 lo, hi;
    lo.x = f2bf(src[0]);    lo.y = f2bf(src[1024]);
    lo.z = f2bf(src[2048]); lo.w = f2bf(src[3072]);
    hi.x = f2bf(src[4096]); hi.y = f2bf(src[5120]);
    hi.z = f2bf(src[6144]); hi.w = f2bf(src[7168]);
    *(ushort4*)(wprojT + (size_t)n*128 + k0)     = lo;
    *(ushort4*)(wprojT + (size_t)n*128 + k0 + 4) = hi;
  }
}

// ---------------- K1: LayerNorm -> xn (bf16), one wave per token ----------------
__global__ __launch_bounds__(256) void k_ln(const float* __restrict__ x,
                                            const float* __restrict__ gamma,
                                            const float* __restrict__ beta,
                                            unsigned short* __restrict__ xn){
  const int tok = (blockIdx.x*256 + threadIdx.x) >> 6;
  const int l = threadIdx.x & 63;
  const float4* xr = (const float4*)(x + (size_t)tok*1024);
  float4 v[4];
  #pragma unroll
  for (int i=0;i<4;i++) v[i] = xr[l + i*64];
  float s = 0.f, s2 = 0.f;
  #pragma unroll
  for (int i=0;i<4;i++){
    s  += v[i].x+v[i].y+v[i].z+v[i].w;
    s2 += v[i].x*v[i].x+v[i].y*v[i].y+v[i].z*v[i].z+v[i].w*v[i].w;
  }
  #pragma unroll
  for (int o=32;o;o>>=1){ s += __shfl_xor(s,o); s2 += __shfl_xor(s2,o); }
  float mu   = s*(1.0f/1024.0f);
  float rstd = rsqrtf(s2*(1.0f/1024.0f) - mu*mu + 1e-5f);
  ushort4* xo = (ushort4*)(xn + (size_t)tok*1024);
  #pragma unroll
  for (int i=0;i<4;i++){
    float4 g = ((const float4*)gamma)[l + i*64];
    float4 b = ((const float4*)beta)[l + i*64];
    ushort4 o;
    o.x = f2bf((v[i].x-mu)*rstd*g.x + b.x);
    o.y = f2bf((v[i].y-mu)*rstd*g.y + b.y);
    o.z = f2bf((v[i].z-mu)*rstd*g.z + b.z);
    o.w = f2bf((v[i].w-mu)*rstd*g.w + b.w);
    xo[l + i*64] = o;
  }
}

// ---------------- K2: QKV GEMM (M=16384,K=1024,N=384), BM=64 BN=128 BK=64 ----------------
// grid (256 m-blocks, 3 sections), 4 waves
__global__ __launch_bounds__(256) void k_qkv(const unsigned short* __restrict__ xn,
                                             const unsigned short* __restrict__ wT,
                                             unsigned short* __restrict__ q,
                                             unsigned short* __restrict__ kbuf,
                                             unsigned short* __restrict__ vT){
  __shared__ __align__(16) unsigned short sm[64*64 + 128*64]; // 24KB
  unsigned short* sA = sm;          // [64 tok][64 k], 128B rows, 16B-chunk XOR (row&7)<<4
  unsigned short* sB = sm + 4096;   // [128 n][64 k], same swizzle
  const int tid = threadIdx.x;
  const int w = tid>>6, l = tid&63;
  const int m0 = blockIdx.x*64;
  const int sec = blockIdx.y;
  const int nb = sec*128;
  const int wm = (w>>1)*32, wn = (w&1)*64;
  f32x4 acc[2][4] = {};
  for (int k0=0; k0<1024; k0+=64){
    #pragma unroll
    for (int i=0;i<2;i++){
      int chunk = i*256 + tid;
      int row = chunk>>3;
      int ch = (tid&7) ^ (row&7);
      GLOAD16(xn + (size_t)(m0+row)*1024 + k0 + ch*8,
              (char*)sA + (i*256 + w*64)*16);
    }
    #pragma unroll
    for (int i=0;i<4;i++){
      int chunk = i*256 + tid;
      int row = chunk>>3;
      int ch = (tid&7) ^ (row&7);
      GLOAD16(wT + (size_t)(nb+row)*1024 + k0 + ch*8,
              (char*)sB + (i*256 + w*64)*16);
    }
    __syncthreads();
    #pragma unroll
    for (int s=0; s<2; ++s){
      short8 af[2], bfr[4];
      #pragma unroll
      for (int i=0;i<2;i++){
        int row = wm + i*16 + (l&15);
        U16B ta; ta.u = *(const uint4*)((const char*)sA + row*128 + ((s*64 + (l>>4)*16) ^ ((row&7)<<4)));
        af[i] = ta.s;
      }
      #pragma unroll
      for (int j=0;j<4;j++){
        int col = wn + j*16 + (l&15);
        U16B tb; tb.u = *(const uint4*)((const char*)sB + col*128 + ((s*64 + (l>>4)*16) ^ ((col&7)<<4)));
        bfr[j] = tb.s;
      }
      #pragma unroll
      for (int i=0;i<2;i++)
        #pragma unroll
        for (int j=0;j<4;j++)
          acc[i][j] = __builtin_amdgcn_mfma_f32_16x16x32_bf16(af[i], bfr[j], acc[i][j], 0,0,0);
    }
    __syncthreads();
  }
  const int b  = m0 >> 10;
  const int n0 = m0 & 1023;
  if (sec < 2){
    // LDS [64 tok][128 f] ushort, 256B rows, 16B-chunk XOR (tok&15)<<4
    #pragma unroll
    for (int fm=0; fm<2; ++fm)
      #pragma unroll
      for (int fn=0; fn<4; ++fn){
        int colf = wn + fn*16 + (l&15);
        #pragma unroll
        for (int i=0;i<4;i++){
          int row = wm + fm*16 + (l>>4)*4 + i;
          *(unsigned short*)((char*)sm + row*256 + ((2*colf) ^ ((row&15)<<4))) = f2bf(acc[fm][fn][i]);
        }
      }
    __syncthreads();
    unsigned short* dst = (sec==0) ? q : kbuf;
    #pragma unroll
    for (int it=0; it<4; ++it){
      int chunk = it*256 + tid;          // 64 rows x 16 chunks
      int tokl = chunk>>4, cc = chunk&15;
      uint4 vv = *(const uint4*)((const char*)sm + tokl*256 + ((cc*16) ^ ((tokl&15)<<4)));
      int h = cc>>1, d0 = (cc&1)*8;
      *(uint4*)(dst + ((size_t)(b*8 + h)*1024 + n0 + tokl)*16 + d0) = vv;
    }
  } else {
    // vT with token bits2<->3 swapped within each 16-group (so attn PV needs no lane weave)
    // LDS [128 f][64 tok] ushort, 128B rows, XOR (f&7)<<4
    #pragma unroll
    for (int fm=0; fm<2; ++fm)
      #pragma unroll
      for (int fn=0; fn<4; ++fn){
        int colf = wn + fn*16 + (l&15);
        int r0 = wm + fm*16 + (l>>4)*4;
        ushort4 pk;
        pk.x = f2bf(acc[fm][fn][0]); pk.y = f2bf(acc[fm][fn][1]);
        pk.z = f2bf(acc[fm][fn][2]); pk.w = f2bf(acc[fm][fn][3]);
        *(ushort4*)((char*)sm + colf*128 + ((2*r0) ^ ((colf&7)<<4))) = pk;
      }
    __syncthreads();
    #pragma unroll
    for (int it=0; it<4; ++it){
      int chunk = it*256 + tid;          // 128 f x 8 chunks
      int f = chunk>>3, cc = chunk&7;
      uint4 vv = *(const uint4*)((const char*)sm + f*128 + ((cc*16) ^ ((f&7)<<4)));
      int h = f>>4, d = f&15;
      unsigned short* dp = vT + ((size_t)(b*8 + h)*16 + d)*1024 + n0 + (cc>>1)*16 + (cc&1)*4;
      *(uint2*)dp       = make_uint2(vv.x, vv.y);
      *(uint2*)(dp + 8) = make_uint2(vv.z, vv.w);
    }
  }
}

// ---------------- K3: flash attention, no-max softmax + MFMA-computed ssum ----------------
// grid (128 bh, 8 qchunk), 4 waves x 32 q-rows
__global__ __launch_bounds__(256) void k_attn(const unsigned short* __restrict__ q,
                                              const unsigned short* __restrict__ kbuf,
                                              const unsigned short* __restrict__ vT,
                                              unsigned short* __restrict__ aout){
  const int bh = blockIdx.x;
  const int qc = blockIdx.y;
  const int w = threadIdx.x>>6, l = threadIdx.x&63;
  const int l31 = l&31, hi = l>>5;
  const int h = bh & 7;
  const int qrow = qc*128 + w*32 + l31;
  U16B qf_u; qf_u.u = *(const uint4*)(q + ((size_t)bh*1024 + qrow)*16 + hi*8);
  const short8 qf = qf_u.s;
  // K walk: row l31 of each 32-token tile, halves by hi
  const unsigned short* kptr = kbuf + (size_t)bh*1024*16 + (size_t)l31*16 + hi*8;
  // V walk: d-row (l31&15); lanes 16,20 inject ones so acc[8] accumulates ssum
  const unsigned short* vptr = vT + (size_t)bh*16*1024 + (size_t)(l31 & 15)*1024 + hi*8;
  const bool vok = (l31 < 16);
  const unsigned int ob = ((l31==16)||(l31==20)) ? 0x3F803F80u : 0u;
  const uint4 cvu = make_uint4(ob, ob, ob, ob);
  f32x16 acc = {};
  U16B kf; kf.u = *(const uint4*)kptr; kptr += 512;
  U16B v0, v1; v0.u = cvu; v1.u = cvu;
  if (vok){ v0.u = *(const uint4*)vptr; v1.u = *(const uint4*)(vptr + 16); }
  vptr += 32;
  #pragma unroll 2
  for (int t=0; t<32; ++t){
    // prefetch next tiles (t=31 over-reads into adjacent ws buffer; value unused)
    U16B kn; kn.u = *(const uint4*)kptr; kptr += 512;
    U16B v0n, v1n; v0n.u = cvu; v1n.u = cvu;
    if (vok){ v0n.u = *(const uint4*)vptr; v1n.u = *(const uint4*)(vptr + 16); }
    vptr += 32;
    f32x16 zz = {};
    f32x16 sv = __builtin_amdgcn_mfma_f32_32x32x16_bf16(kf.s, qf, zz, 0,0,0);
    // no-max softmax: P = exp2(s) directly (|s| small; fp32 exp2 safe to s<127)
    float p[16];
    #pragma unroll
    for (int r=0;r<16;r++){ p[r] = __builtin_amdgcn_exp2f(sv[r]); }
    unsigned int u[8];
    #pragma unroll
    for (int j=0;j<8;j++){
      asm("v_cvt_pk_bf16_f32 %0, %1, %2" : "=v"(u[j]) : "v"(p[2*j]), "v"(p[2*j+1]));
    }
    U16B p0, p1;
    p0.u.x = u[0]; p0.u.y = u[1]; p0.u.z = u[2]; p0.u.w = u[3];
    p1.u.x = u[4]; p1.u.y = u[5]; p1.u.z = u[6]; p1.u.w = u[7];
    acc = __builtin_amdgcn_mfma_f32_32x32x16_bf16(v0.s, p0.s, acc, 0,0,0);
    acc = __builtin_amdgcn_mfma_f32_32x32x16_bf16(v1.s, p1.s, acc, 0,0,0);
    kf = kn; v0 = v0n; v1 = v1n;
  }
  // acc[8] = ssum (C-row 16 for hi=0, row 20 for hi=1 — both fed by ones-rows of V)
  float inv = 1.0f/acc[8];
  const size_t tok = (size_t)(bh>>3)*1024 + qrow;
  ushort4 o;
  o.x = f2bf(acc[0]*inv); o.y = f2bf(acc[1]*inv); o.z = f2bf(acc[2]*inv); o.w = f2bf(acc[3]*inv);
  *(ushort4*)(aout + tok*128 + h*16 + hi*4) = o;
  o.x = f2bf(acc[4]*inv); o.y = f2bf(acc[5]*inv); o.z = f2bf(acc[6]*inv); o.w = f2bf(acc[7]*inv);
  *(ushort4*)(aout + tok*128 + h*16 + 8 + hi*4) = o;
}

// ---------------- K4: out-projection (M=16384,K=128,N=1024) + bias ----------------
__global__ __launch_bounds__(256) void k_proj(const unsigned short* __restrict__ aout,
                                              const unsigned short* __restrict__ wT, // [1024 n][128 k]
                                              const float* __restrict__ bias,
                                              float* __restrict__ out){
  __shared__ __align__(16) unsigned short sA[128*128]; // [tok][k], 256B rows, XOR (row&15)<<4
  __shared__ __align__(16) unsigned short sB[128*128]; // [n][k], same
  const int tid = threadIdx.x;
  const int w = tid>>6, l = tid&63;
  const int m0 = blockIdx.x*128, nb = blockIdx.y*128;
  #pragma unroll
  for (int i=0;i<8;i++){
    int chunk = i*256 + tid;
    int row = chunk>>4;
    int ch = (tid&15) ^ (row&15);
    GLOAD16(aout + (size_t)(m0+row)*128 + ch*8, (char*)sA + (i*256 + w*64)*16);
  }
  #pragma unroll
  for (int i=0;i<8;i++){
    int chunk = i*256 + tid;
    int row = chunk>>4;
    int ch = (tid&15) ^ (row&15);
    GLOAD16(wT + (size_t)(nb+row)*128 + ch*8, (char*)sB + (i*256 + w*64)*16);
  }
  __syncthreads();
  const int wm = (w>>1)*64, wn = (w&1)*64;
  f32x4 acc[4][4] = {};
  #pragma unroll
  for (int s=0; s<4; ++s){
    short8 af[4], bfr[4];
    #pragma unroll
    for (int i=0;i<4;i++){
      int row = wm + i*16 + (l&15);
      U16B ta; ta.u = *(const uint4*)((const char*)sA + row*256 + ((s*64 + (l>>4)*16) ^ ((row&15)<<4)));
      af[i] = ta.s;
      int col = wn + i*16 + (l&15);
      U16B tb; tb.u = *(const uint4*)((const char*)sB + col*256 + ((s*64 + (l>>4)*16) ^ ((col&15)<<4)));
      bfr[i] = tb.s;
    }
    #pragma unroll
    for (int i=0;i<4;i++)
      #pragma unroll
      for (int j=0;j<4;j++)
        acc[i][j] = __builtin_amdgcn_mfma_f32_16x16x32_bf16(af[i], bfr[j], acc[i][j], 0,0,0);
  }
  #pragma unroll
  for (int fn=0; fn<4; ++fn){
    int col = nb + wn + fn*16 + (l&15);
    float bv = bias[col];
    #pragma unroll
    for (int fm=0; fm<4; ++fm)
      #pragma unroll
      for (int i=0;i<4;i++)
        out[(size_t)(m0 + wm + fm*16 + (l>>4)*4 + i)*1024 + col] = acc[fm][fn][i] + bv;
  }
}

extern "C" void kernel_launch(void* const* d_in, const int* in_sizes, int n_in,
                              void* d_out, int out_size, void* d_ws, size_t ws_size,
                              hipStream_t stream){
  (void)in_sizes; (void)n_in; (void)out_size; (void)ws_size;
  const float* x     = (const float*)d_in[0];
  const float* gamma = (const float*)d_in[1];
  const float* beta  = (const float*)d_in[2];
  const float* wqkv  = (const float*)d_in[3];
  const float* wproj = (const float*)d_in[4];
  const float* bias  = (const float*)d_in[5];
  float* out = (float*)d_out;
  char* ws = (char*)d_ws;
  unsigned short* xn = (unsigned short*)ws;                                  // 32 MB
  unsigned short* q  = (unsigned short*)(ws + 33554432);                     // 4 MB
  unsigned short* kb = (unsigned short*)(ws + 33554432 + 4194304);           // 4 MB
  unsigned short* vT = (unsigned short*)(ws + 33554432 + 2*4194304);         // 4 MB
  unsigned short* ao = (unsigned short*)(ws + 33554432 + 3*4194304);         // 4 MB
  unsigned short* wqkvT = (unsigned short*)(ws + 33554432 + 4*4194304);      // 768 KB
  unsigned short* wprojT = (unsigned short*)(ws + 33554432 + 4*4194304 + 786432); // 256 KB
  k_cvtw<<<dim3(256), dim3(256), 0, stream>>>(wqkv, wproj, wqkvT, wprojT);
  k_ln  <<<dim3(4096), dim3(256), 0, stream>>>(x, gamma, beta, xn);
  k_qkv <<<dim3(256,3), dim3(256), 0, stream>>>(xn, wqkvT, q, kb, vT);
  k_attn<<<dim3(128,8), dim3(256), 0, stream>>>(q, kb, vT, ao);
  k_proj<<<dim3(128,8), dim3(256), 0, stream>>>(ao, wprojT, bias, out);
}

// Round 5
// 89.881 us; speedup vs baseline: 1.6204x; 1.0215x over previous
//
#include <hip/hip_runtime.h>

// Dims: b=16, n=1024, EMB=1024, INNER=128, HEADS=8, HD=16
#define LOG2E 1.44269504088896340736f
#define QSCALE (0.08838834764831845f * LOG2E)   // INNER^-0.5 * log2(e)

using short8 = __attribute__((ext_vector_type(8))) short;
using f32x4  = __attribute__((ext_vector_type(4))) float;
using f32x16 = __attribute__((ext_vector_type(16))) float;

union U16B { uint4 u; short8 s; };

typedef __attribute__((address_space(3))) unsigned char lds_byte;
typedef const __attribute__((address_space(1))) unsigned char glb_byte;
#define GLOAD16(gp, lp) __builtin_amdgcn_global_load_lds((glb_byte*)(gp), (lds_byte*)(lp), 16, 0, 0)

static __device__ __forceinline__ unsigned short f2bf(float f){
  union { float f; unsigned int i; } c; c.f = f;
  unsigned int i = c.i;
  i += 0x7fffu + ((i >> 16) & 1u);   // RNE
  return (unsigned short)(i >> 16);
}

// ---------------- K1: LayerNorm (blocks 0..4095) + weight cvt (blocks 4096..4351) ----------------
__global__ __launch_bounds__(256) void k_ln(const float* __restrict__ x,
                                            const float* __restrict__ gamma,
                                            const float* __restrict__ beta,
                                            unsigned short* __restrict__ xn,
                                            const float* __restrict__ wqkv,
                                            const float* __restrict__ wproj,
                                            unsigned short* __restrict__ wqkvT,
                                            unsigned short* __restrict__ wprojT){
  if (blockIdx.x < 4096){
    const int tok = (blockIdx.x*256 + threadIdx.x) >> 6;
    const int l = threadIdx.x & 63;
    const float4* xr = (const float4*)(x + (size_t)tok*1024);
    float4 v[4];
    #pragma unroll
    for (int i=0;i<4;i++) v[i] = xr[l + i*64];
    float s = 0.f, s2 = 0.f;
    #pragma unroll
    for (int i=0;i<4;i++){
      s  += v[i].x+v[i].y+v[i].z+v[i].w;
      s2 += v[i].x*v[i].x+v[i].y*v[i].y+v[i].z*v[i].z+v[i].w*v[i].w;
    }
    #pragma unroll
    for (int o=32;o;o>>=1){ s += __shfl_xor(s,o); s2 += __shfl_xor(s2,o); }
    float mu   = s*(1.0f/1024.0f);
    float rstd = rsqrtf(s2*(1.0f/1024.0f) - mu*mu + 1e-5f);
    ushort4* xo = (ushort4*)(xn + (size_t)tok*1024);
    #pragma unroll
    for (int i=0;i<4;i++){
      float4 g = ((const float4*)gamma)[l + i*64];
      float4 b = ((const float4*)beta)[l + i*64];
      ushort4 o;
      o.x = f2bf((v[i].x-mu)*rstd*g.x + b.x);
      o.y = f2bf((v[i].y-mu)*rstd*g.y + b.y);
      o.z = f2bf((v[i].z-mu)*rstd*g.z + b.z);
      o.w = f2bf((v[i].w-mu)*rstd*g.w + b.w);
      xo[l + i*64] = o;
    }
  } else {
    int t = (blockIdx.x - 4096)*256 + threadIdx.x;
    if (t < 49152){
      int n = t>>7, k0 = (t&127)*8;
      float sc = (n < 128) ? QSCALE : 1.0f;
      const float* src = wqkv + (size_t)k0*384 + n;
      ushort4 lo, hi;
      lo.x = f2bf(src[0]*sc);    lo.y = f2bf(src[384]*sc);
      lo.z = f2bf(src[768]*sc);  lo.w = f2bf(src[1152]*sc);
      hi.x = f2bf(src[1536]*sc); hi.y = f2bf(src[1920]*sc);
      hi.z = f2bf(src[2304]*sc); hi.w = f2bf(src[2688]*sc);
      *(ushort4*)(wqkvT + (size_t)n*1024 + k0)     = lo;
      *(ushort4*)(wqkvT + (size_t)n*1024 + k0 + 4) = hi;
    } else {
      int t2 = t - 49152;
      int n = t2>>4, k0 = (t2&15)*8;
      const float* src = wproj + (size_t)k0*1024 + n;
      ushort4 lo, hi;
      lo.x = f2bf(src[0]);    lo.y = f2bf(src[1024]);
      lo.z = f2bf(src[2048]); lo.w = f2bf(src[3072]);
      hi.x = f2bf(src[4096]); hi.y = f2bf(src[5120]);
      hi.z = f2bf(src[6144]); hi.w = f2bf(src[7168]);
      *(ushort4*)(wprojT + (size_t)n*128 + k0)     = lo;
      *(ushort4*)(wprojT + (size_t)n*128 + k0 + 4) = hi;
    }
  }
}

// ---------------- K2: QKV GEMM (M=16384,K=1024,N=384), BM=64 BN=128 BK=64 ----------------
// grid (256 m-blocks, 3 sections), 4 waves; double-buffered 2-phase, counted vmcnt
__global__ __launch_bounds__(256) void k_qkv(const unsigned short* __restrict__ xn,
                                             const unsigned short* __restrict__ wT,
                                             unsigned short* __restrict__ q,
                                             unsigned short* __restrict__ kbuf,
                                             unsigned short* __restrict__ vT){
  __shared__ __align__(16) unsigned short sm[2][64*64 + 128*64]; // 2 x 24KB
  const int tid = threadIdx.x;
  const int w = tid>>6, l = tid&63;
  const int m0 = blockIdx.x*64;
  const int sec = blockIdx.y;
  const int nb = sec*128;
  const int wm = (w>>1)*32, wn = (w&1)*64;
  f32x4 acc[2][4] = {};

  // stage tile k0 into buffer buf (6 gloads/thread: 2 A + 4 B)
  auto stage = [&](int buf, int k0){
    unsigned short* sA = &sm[buf][0];
    unsigned short* sB = &sm[buf][4096];
    #pragma unroll
    for (int i=0;i<2;i++){
      int chunk = i*256 + tid;
      int row = chunk>>3;
      int ch = (tid&7) ^ (row&7);
      GLOAD16(xn + (size_t)(m0+row)*1024 + k0 + ch*8,
              (char*)sA + (i*256 + w*64)*16);
    }
    #pragma unroll
    for (int i=0;i<4;i++){
      int chunk = i*256 + tid;
      int row = chunk>>3;
      int ch = (tid&7) ^ (row&7);
      GLOAD16(wT + (size_t)(nb+row)*1024 + k0 + ch*8,
              (char*)sB + (i*256 + w*64)*16);
    }
  };

  stage(0, 0);
  for (int t=0; t<16; ++t){
    const int cur = t & 1;
    if (t < 15){
      stage(cur^1, (t+1)<<6);
      asm volatile("s_waitcnt vmcnt(6)" ::: "memory");   // current tile's 6 loads done
    } else {
      asm volatile("s_waitcnt vmcnt(0)" ::: "memory");
    }
    __builtin_amdgcn_s_barrier();
    const unsigned short* sA = &sm[cur][0];
    const unsigned short* sB = &sm[cur][4096];
    #pragma unroll
    for (int s=0; s<2; ++s){
      short8 af[2], bfr[4];
      #pragma unroll
      for (int i=0;i<2;i++){
        int row = wm + i*16 + (l&15);
        U16B ta; ta.u = *(const uint4*)((const char*)sA + row*128 + ((s*64 + (l>>4)*16) ^ ((row&7)<<4)));
        af[i] = ta.s;
      }
      #pragma unroll
      for (int j=0;j<4;j++){
        int col = wn + j*16 + (l&15);
        U16B tb; tb.u = *(const uint4*)((const char*)sB + col*128 + ((s*64 + (l>>4)*16) ^ ((col&7)<<4)));
        bfr[j] = tb.s;
      }
      #pragma unroll
      for (int i=0;i<2;i++)
        #pragma unroll
        for (int j=0;j<4;j++)
          acc[i][j] = __builtin_amdgcn_mfma_f32_16x16x32_bf16(af[i], bfr[j], acc[i][j], 0,0,0);
    }
    __builtin_amdgcn_s_barrier();   // reads of buf[cur] done before t+1 overwrites it
  }

  const int b  = m0 >> 10;
  const int n0 = m0 & 1023;
  unsigned short* ep = &sm[0][0];
  if (sec < 2){
    // LDS [64 tok][128 f] ushort, 256B rows, 16B-chunk XOR (tok&15)<<4
    #pragma unroll
    for (int fm=0; fm<2; ++fm)
      #pragma unroll
      for (int fn=0; fn<4; ++fn){
        int colf = wn + fn*16 + (l&15);
        #pragma unroll
        for (int i=0;i<4;i++){
          int row = wm + fm*16 + (l>>4)*4 + i;
          *(unsigned short*)((char*)ep + row*256 + ((2*colf) ^ ((row&15)<<4))) = f2bf(acc[fm][fn][i]);
        }
      }
    __syncthreads();
    unsigned short* dst = (sec==0) ? q : kbuf;
    #pragma unroll
    for (int it=0; it<4; ++it){
      int chunk = it*256 + tid;          // 64 rows x 16 chunks
      int tokl = chunk>>4, cc = chunk&15;
      uint4 vv = *(const uint4*)((const char*)ep + tokl*256 + ((cc*16) ^ ((tokl&15)<<4)));
      int h = cc>>1, d0 = (cc&1)*8;
      *(uint4*)(dst + ((size_t)(b*8 + h)*1024 + n0 + tokl)*16 + d0) = vv;
    }
  } else {
    // vT with token bits2<->3 swapped within each 16-group (attn PV needs no lane weave)
    // LDS [128 f][64 tok] ushort, 128B rows, XOR (f&7)<<4
    #pragma unroll
    for (int fm=0; fm<2; ++fm)
      #pragma unroll
      for (int fn=0; fn<4; ++fn){
        int colf = wn + fn*16 + (l&15);
        int r0 = wm + fm*16 + (l>>4)*4;
        ushort4 pk;
        pk.x = f2bf(acc[fm][fn][0]); pk.y = f2bf(acc[fm][fn][1]);
        pk.z = f2bf(acc[fm][fn][2]); pk.w = f2bf(acc[fm][fn][3]);
        *(ushort4*)((char*)ep + colf*128 + ((2*r0) ^ ((colf&7)<<4))) = pk;
      }
    __syncthreads();
    #pragma unroll
    for (int it=0; it<4; ++it){
      int chunk = it*256 + tid;          // 128 f x 8 chunks
      int f = chunk>>3, cc = chunk&7;
      uint4 vv = *(const uint4*)((const char*)ep + f*128 + ((cc*16) ^ ((f&7)<<4)));
      int h = f>>4, d = f&15;
      unsigned short* dp = vT + ((size_t)(b*8 + h)*16 + d)*1024 + n0 + (cc>>1)*16 + (cc&1)*4;
      *(uint2*)dp       = make_uint2(vv.x, vv.y);
      *(uint2*)(dp + 8) = make_uint2(vv.z, vv.w);
    }
  }
}

// ---------------- K3: flash attention, pipelined QK^T || softmax, MFMA ssum ----------------
// grid (128 bh, 8 qchunk), 4 waves x 32 q-rows
__global__ __launch_bounds__(256) void k_attn(const unsigned short* __restrict__ q,
                                              const unsigned short* __restrict__ kbuf,
                                              const unsigned short* __restrict__ vT,
                                              unsigned short* __restrict__ aout){
  const int bh = blockIdx.x;
  const int qc = blockIdx.y;
  const int w = threadIdx.x>>6, l = threadIdx.x&63;
  const int l31 = l&31, hi = l>>5;
  const int h = bh & 7;
  const int qrow = qc*128 + w*32 + l31;
  U16B qf_u; qf_u.u = *(const uint4*)(q + ((size_t)bh*1024 + qrow)*16 + hi*8);
  const short8 qf = qf_u.s;
  const unsigned short* kptr = kbuf + (size_t)bh*1024*16 + (size_t)l31*16 + hi*8;
  const unsigned short* vptr = vT + (size_t)bh*16*1024 + (size_t)(l31 & 15)*1024 + hi*8;
  const bool vok = (l31 < 16);
  const unsigned int ob = ((l31==16)||(l31==20)) ? 0x3F803F80u : 0u;
  const uint4 cvu = make_uint4(ob, ob, ob, ob);
  f32x16 acc = {};
  const f32x16 zz = {};

  // prologue: K tiles 0,1; V tile 0; scores for tile 0
  U16B kf; kf.u = *(const uint4*)kptr; kptr += 512;
  U16B kn; kn.u = *(const uint4*)kptr; kptr += 512;
  U16B v0, v1; v0.u = cvu; v1.u = cvu;
  if (vok){ v0.u = *(const uint4*)vptr; v1.u = *(const uint4*)(vptr + 16); }
  vptr += 32;
  f32x16 sv = __builtin_amdgcn_mfma_f32_32x32x16_bf16(kf.s, qf, zz, 0,0,0);

  for (int t=0; t<32; ++t){
    // prefetch K tile t+2, V tile t+1 (tail over-reads land in adjacent ws buffers)
    U16B knn; knn.u = *(const uint4*)kptr; kptr += 512;
    U16B v0n, v1n; v0n.u = cvu; v1n.u = cvu;
    if (vok){ v0n.u = *(const uint4*)vptr; v1n.u = *(const uint4*)(vptr + 16); }
    vptr += 32;
    // issue next tile's QK^T on the MFMA pipe before this tile's softmax (VALU)
    f32x16 svn = __builtin_amdgcn_mfma_f32_32x32x16_bf16(kn.s, qf, zz, 0,0,0);
    // no-max softmax: P = exp2(s), fused exp->cvt_pk (no p[] array)
    unsigned int u[8];
    #pragma unroll
    for (int j=0;j<8;j++){
      float a = __builtin_amdgcn_exp2f(sv[2*j]);
      float b = __builtin_amdgcn_exp2f(sv[2*j+1]);
      asm("v_cvt_pk_bf16_f32 %0, %1, %2" : "=v"(u[j]) : "v"(a), "v"(b));
    }
    U16B p0, p1;
    p0.u.x = u[0]; p0.u.y = u[1]; p0.u.z = u[2]; p0.u.w = u[3];
    p1.u.x = u[4]; p1.u.y = u[5]; p1.u.z = u[6]; p1.u.w = u[7];
    __builtin_amdgcn_s_setprio(1);
    acc = __builtin_amdgcn_mfma_f32_32x32x16_bf16(v0.s, p0.s, acc, 0,0,0);
    acc = __builtin_amdgcn_mfma_f32_32x32x16_bf16(v1.s, p1.s, acc, 0,0,0);
    __builtin_amdgcn_s_setprio(0);
    sv = svn; kn = knn; v0 = v0n; v1 = v1n;
  }
  // acc[8] = ssum (ones-rows 16/20 of the V operand)
  float inv = 1.0f/acc[8];
  const size_t tok = (size_t)(bh>>3)*1024 + qrow;
  ushort4 o;
  o.x = f2bf(acc[0]*inv); o.y = f2bf(acc[1]*inv); o.z = f2bf(acc[2]*inv); o.w = f2bf(acc[3]*inv);
  *(ushort4*)(aout + tok*128 + h*16 + hi*4) = o;
  o.x = f2bf(acc[4]*inv); o.y = f2bf(acc[5]*inv); o.z = f2bf(acc[6]*inv); o.w = f2bf(acc[7]*inv);
  *(ushort4*)(aout + tok*128 + h*16 + 8 + hi*4) = o;
}

// ---------------- K4: out-projection (M=16384,K=128,N=1024) + bias ----------------
__global__ __launch_bounds__(256) void k_proj(const unsigned short* __restrict__ aout,
                                              const unsigned short* __restrict__ wT, // [1024 n][128 k]
                                              const float* __restrict__ bias,
                                              float* __restrict__ out){
  __shared__ __align__(16) unsigned short sA[128*128]; // [tok][k], 256B rows, XOR (row&15)<<4
  __shared__ __align__(16) unsigned short sB[128*128]; // [n][k], same
  const int tid = threadIdx.x;
  const int w = tid>>6, l = tid&63;
  const int m0 = blockIdx.x*128, nb = blockIdx.y*128;
  #pragma unroll
  for (int i=0;i<8;i++){
    int chunk = i*256 + tid;
    int row = chunk>>4;
    int ch = (tid&15) ^ (row&15);
    GLOAD16(aout + (size_t)(m0+row)*128 + ch*8, (char*)sA + (i*256 + w*64)*16);
  }
  #pragma unroll
  for (int i=0;i<8;i++){
    int chunk = i*256 + tid;
    int row = chunk>>4;
    int ch = (tid&15) ^ (row&15);
    GLOAD16(wT + (size_t)(nb+row)*128 + ch*8, (char*)sB + (i*256 + w*64)*16);
  }
  __syncthreads();
  const int wm = (w>>1)*64, wn = (w&1)*64;
  f32x4 acc[4][4] = {};
  #pragma unroll
  for (int s=0; s<4; ++s){
    short8 af[4], bfr[4];
    #pragma unroll
    for (int i=0;i<4;i++){
      int row = wm + i*16 + (l&15);
      U16B ta; ta.u = *(const uint4*)((const char*)sA + row*256 + ((s*64 + (l>>4)*16) ^ ((row&15)<<4)));
      af[i] = ta.s;
      int col = wn + i*16 + (l&15);
      U16B tb; tb.u = *(const uint4*)((const char*)sB + col*256 + ((s*64 + (l>>4)*16) ^ ((col&15)<<4)));
      bfr[i] = tb.s;
    }
    #pragma unroll
    for (int i=0;i<4;i++)
      #pragma unroll
      for (int j=0;j<4;j++)
        acc[i][j] = __builtin_amdgcn_mfma_f32_16x16x32_bf16(af[i], bfr[j], acc[i][j], 0,0,0);
  }
  #pragma unroll
  for (int fn=0; fn<4; ++fn){
    int col = nb + wn + fn*16 + (l&15);
    float bv = bias[col];
    #pragma unroll
    for (int fm=0; fm<4; ++fm)
      #pragma unroll
      for (int i=0;i<4;i++)
        out[(size_t)(m0 + wm + fm*16 + (l>>4)*4 + i)*1024 + col] = acc[fm][fn][i] + bv;
  }
}

extern "C" void kernel_launch(void* const* d_in, const int* in_sizes, int n_in,
                              void* d_out, int out_size, void* d_ws, size_t ws_size,
                              hipStream_t stream){
  (void)in_sizes; (void)n_in; (void)out_size; (void)ws_size;
  const float* x     = (const float*)d_in[0];
  const float* gamma = (const float*)d_in[1];
  const float* beta  = (const float*)d_in[2];
  const float* wqkv  = (const float*)d_in[3];
  const float* wproj = (const float*)d_in[4];
  const float* bias  = (const float*)d_in[5];
  float* out = (float*)d_out;
  char* ws = (char*)d_ws;
  unsigned short* xn = (unsigned short*)ws;                                  // 32 MB
  unsigned short* q  = (unsigned short*)(ws + 33554432);                     // 4 MB
  unsigned short* kb = (unsigned short*)(ws + 33554432 + 4194304);           // 4 MB
  unsigned short* vT = (unsigned short*)(ws + 33554432 + 2*4194304);         // 4 MB
  unsigned short* ao = (unsigned short*)(ws + 33554432 + 3*4194304);         // 4 MB
  unsigned short* wqkvT = (unsigned short*)(ws + 33554432 + 4*4194304);      // 768 KB
  unsigned short* wprojT = (unsigned short*)(ws + 33554432 + 4*4194304 + 786432); // 256 KB
  k_ln  <<<dim3(4352), dim3(256), 0, stream>>>(x, gamma, beta, xn, wqkv, wproj, wqkvT, wprojT);
  k_qkv <<<dim3(256,3), dim3(256), 0, stream>>>(xn, wqkvT, q, kb, vT);
  k_attn<<<dim3(128,8), dim3(256), 0, stream>>>(q, kb, vT, ao);
  k_proj<<<dim3(128,8), dim3(256), 0, stream>>>(ao, wprojT, bias, out);
}